// Round 1
// baseline (294.072 us; speedup 1.0000x reference)
//
#include <hip/hip_runtime.h>
#include <hip/hip_bf16.h>

// LowRankSoftmaxAttentionBlock: B=8, N=4096, D=H=256, BLOCK_SIZE=128, BLOCK_K=64
// Pipeline: prep(bf16 weights) -> LN1 -> QKV gemm -> l2norm(Q,K) ->
//           Kproj [k][h], VprojT [h][k] -> attention (flash, no-max softmax) ->
//           outproj + residual + LN2.
// All matmuls: v_mfma_f32_16x16x32_bf16, f32 accum.
// Layouts (verified m89/m74): A/B frag: own-idx = lane&15, k = (lane>>4)*8+j (contiguous 8)
//                             C/D: col = lane&15, row = (lane>>4)*4 + reg

typedef __bf16 bf16;
typedef __bf16 v8bf __attribute__((ext_vector_type(8)));
typedef __bf16 v4bf __attribute__((ext_vector_type(4)));
typedef float  v4f  __attribute__((ext_vector_type(4)));

#define MFMA(a,b,c) __builtin_amdgcn_mfma_f32_16x16x32_bf16((a),(b),(c),0,0,0)

// ---------------- K0: convert weights to bf16 ----------------
__global__ __launch_bounds__(256) void k_prep(const float* __restrict__ wq, const float* __restrict__ wk,
                       const float* __restrict__ wv, const float* __restrict__ wo,
                       const float* __restrict__ E,  const float* __restrict__ F,
                       bf16* __restrict__ wqkv, bf16* __restrict__ wob,
                       bf16* __restrict__ ebf,  bf16* __restrict__ fbf){
  int i = blockIdx.x * 256 + threadIdx.x;          // 0..196607
  float v;
  if (i < 65536)       v = wq[i];
  else if (i < 131072) v = wk[i - 65536];
  else                 v = wv[i - 131072];
  wqkv[i] = (bf16)v;
  if (i < 65536) wob[i] = (bf16)wo[i];
  if (i < 8192) { ebf[i] = (bf16)E[i]; fbf[i] = (bf16)F[i]; }
}

// ---------------- K1: LayerNorm1 -> tn (bf16) ----------------
__global__ __launch_bounds__(256) void k_ln1(const float* __restrict__ tok, const float* __restrict__ g1,
                      const float* __restrict__ b1, bf16* __restrict__ tn){
  int row  = blockIdx.x * 4 + (threadIdx.x >> 6);
  int lane = threadIdx.x & 63;
  float4 x = *reinterpret_cast<const float4*>(tok + (size_t)row * 256 + lane * 4);
  float s  = x.x + x.y + x.z + x.w;
  float ss = x.x*x.x + x.y*x.y + x.z*x.z + x.w*x.w;
  for (int o = 1; o < 64; o <<= 1) { s += __shfl_xor(s, o); ss += __shfl_xor(ss, o); }
  float mean = s * (1.0f/256.0f);
  float var  = ss * (1.0f/256.0f) - mean*mean;
  float inv  = rsqrtf(var + 1e-5f);
  float4 g  = *reinterpret_cast<const float4*>(g1 + lane*4);
  float4 bb = *reinterpret_cast<const float4*>(b1 + lane*4);
  v4bf o4;
  o4[0] = (bf16)((x.x-mean)*inv*g.x + bb.x);
  o4[1] = (bf16)((x.y-mean)*inv*g.y + bb.y);
  o4[2] = (bf16)((x.z-mean)*inv*g.z + bb.z);
  o4[3] = (bf16)((x.w-mean)*inv*g.w + bb.w);
  *reinterpret_cast<v4bf*>(tn + (size_t)row * 256 + lane * 4) = o4;
}

// ---------------- K2: QKV GEMM: C[32768,768] = tn[32768,256] @ Wqkv[768,256]^T ----------------
__global__ __launch_bounds__(256) void k_qkv(const bf16* __restrict__ tn, const bf16* __restrict__ w,
                                             bf16* __restrict__ qkv){
  int bm = blockIdx.x, bn = blockIdx.y;
  int wid = threadIdx.x >> 6, lane = threadIdx.x & 63;
  int wr = wid >> 1, wc = wid & 1;
  int row0 = bm * 128 + wr * 64;
  int col0 = bn * 128 + wc * 64;
  int lr = lane & 15, lg = lane >> 4;
  v4f acc[4][4] = {};
  for (int k0 = 0; k0 < 256; k0 += 32) {
    v8bf a[4], b[4];
#pragma unroll
    for (int mi = 0; mi < 4; mi++)
      a[mi] = *reinterpret_cast<const v8bf*>(tn + (size_t)(row0 + mi*16 + lr) * 256 + k0 + lg*8);
#pragma unroll
    for (int ni = 0; ni < 4; ni++)
      b[ni] = *reinterpret_cast<const v8bf*>(w + (size_t)(col0 + ni*16 + lr) * 256 + k0 + lg*8);
#pragma unroll
    for (int mi = 0; mi < 4; mi++)
#pragma unroll
      for (int ni = 0; ni < 4; ni++)
        acc[mi][ni] = MFMA(a[mi], b[ni], acc[mi][ni]);
  }
#pragma unroll
  for (int mi = 0; mi < 4; mi++)
#pragma unroll
    for (int ni = 0; ni < 4; ni++) {
      int r = row0 + mi*16 + lg*4;
      int c = col0 + ni*16 + lr;
#pragma unroll
      for (int q = 0; q < 4; q++)
        qkv[(size_t)(r + q) * 768 + c] = (bf16)acc[mi][ni][q];
    }
}

// ---------------- K3: row l2norm of Q and K (in place) ----------------
__global__ __launch_bounds__(256) void k_l2n(bf16* __restrict__ qkv){
  int t    = blockIdx.x * 4 + (threadIdx.x >> 6);   // 0..65535
  int lane = threadIdx.x & 63;
  int row  = t & 32767, seg = t >> 15;              // seg 0=Q, 1=K
  bf16* p = qkv + (size_t)row * 768 + seg * 256 + lane * 4;
  v4bf x = *reinterpret_cast<v4bf*>(p);
  float f0 = (float)x[0], f1 = (float)x[1], f2 = (float)x[2], f3 = (float)x[3];
  float ss = f0*f0 + f1*f1 + f2*f2 + f3*f3;
  for (int o = 1; o < 64; o <<= 1) ss += __shfl_xor(ss, o);
  float sc = 1.0f / fmaxf(sqrtf(ss), 1e-12f);
  x[0] = (bf16)(f0*sc); x[1] = (bf16)(f1*sc); x[2] = (bf16)(f2*sc); x[3] = (bf16)(f3*sc);
  *reinterpret_cast<v4bf*>(p) = x;
}

// ---------------- K4a: K_proj[b*2048+k][h] = sum_s E[k,s] * K[b,blk*128+s][h] ----------------
__global__ __launch_bounds__(256) void k_kproj(const bf16* __restrict__ qkv, const bf16* __restrict__ ebf,
                                               bf16* __restrict__ kp){
  int b = blockIdx.x >> 5, blk = blockIdx.x & 31;
  int w = threadIdx.x >> 6, lane = threadIdx.x & 63;
  int lr = lane & 15, lg = lane >> 4;
  const bf16* kb = qkv + (size_t)(b*4096 + blk*128) * 768 + 256;  // [128 s][256 h] stride 768
  v8bf a[4];
#pragma unroll
  for (int sc = 0; sc < 4; sc++)   // A = E: row k = w*16+lr, s contiguous
    a[sc] = *reinterpret_cast<const v8bf*>(ebf + (size_t)(w*16 + lr) * 128 + sc*32 + lg*8);
  v4f acc[16] = {};
#pragma unroll
  for (int nt = 0; nt < 16; nt++) {
#pragma unroll
    for (int sc = 0; sc < 4; sc++) {
      v8bf bfrag;
#pragma unroll
      for (int j = 0; j < 8; j++)  // B[s][h]: h = lr (own idx), s = sc*32+lg*8+j
        bfrag[j] = kb[(size_t)(sc*32 + lg*8 + j) * 768 + nt*16 + lr];
      acc[nt] = MFMA(a[sc], bfrag, acc[nt]);
    }
  }
  int krow = b*2048 + blk*64 + w*16 + lg*4;
#pragma unroll
  for (int nt = 0; nt < 16; nt++)
#pragma unroll
    for (int q = 0; q < 4; q++)
      kp[(size_t)(krow + q) * 256 + nt*16 + lr] = (bf16)acc[nt][q];
}

// ---------------- K4b: VprojT[b*256+h][k_global] = sum_s F[k,s] * V[b,blk*128+s][h] ----------------
__global__ __launch_bounds__(256) void k_vproj(const bf16* __restrict__ qkv, const bf16* __restrict__ fbf,
                                               bf16* __restrict__ vpt){
  int b = blockIdx.x >> 5, blk = blockIdx.x & 31;
  int w = threadIdx.x >> 6, lane = threadIdx.x & 63;
  int lr = lane & 15, lg = lane >> 4;
  const bf16* vb = qkv + (size_t)(b*4096 + blk*128) * 768 + 512;  // [128 s][256 h] stride 768
  v8bf bf_[4][4];  // B[s][k]: k = lr (own idx), s contiguous -> F rows
#pragma unroll
  for (int ni = 0; ni < 4; ni++)
#pragma unroll
    for (int sc = 0; sc < 4; sc++)
      bf_[ni][sc] = *reinterpret_cast<const v8bf*>(fbf + (size_t)(ni*16 + lr) * 128 + sc*32 + lg*8);
  v4f acc[4][4] = {};
#pragma unroll
  for (int mi = 0; mi < 4; mi++) {
    int h = (w*4 + mi) * 16 + lr;   // A[h][s] = V[s][h]
#pragma unroll
    for (int sc = 0; sc < 4; sc++) {
      v8bf a;
#pragma unroll
      for (int j = 0; j < 8; j++)
        a[j] = vb[(size_t)(sc*32 + lg*8 + j) * 768 + h];
#pragma unroll
      for (int ni = 0; ni < 4; ni++)
        acc[mi][ni] = MFMA(a, bf_[ni][sc], acc[mi][ni]);
    }
  }
#pragma unroll
  for (int mi = 0; mi < 4; mi++)
#pragma unroll
    for (int ni = 0; ni < 4; ni++)
#pragma unroll
      for (int q = 0; q < 4; q++)
        vpt[(size_t)(b*256 + (w*4 + mi)*16 + lg*4 + q) * 2048 + blk*64 + ni*16 + lr] = (bf16)acc[mi][ni][q];
}

// ---------------- K5: attention. 1 block = 128 Q rows, 8 waves x 16 rows ----------------
__global__ __launch_bounds__(512) void k_attn(const bf16* __restrict__ qkv, const bf16* __restrict__ kp,
                                              const bf16* __restrict__ vpt, const float* __restrict__ scalep,
                                              bf16* __restrict__ attn){
  __shared__ __align__(16) bf16 Ks[64 * 256];   // Kp chunk, XOR-swizzled 16B units
  __shared__ __align__(16) bf16 Vs[256 * 64];   // VpT chunk, XOR-swizzled 16B units
  __shared__ __align__(16) bf16 Ps[8][16 * 64]; // per-wave P (swizzled)
  int b = blockIdx.x >> 5, mb = blockIdx.x & 31;
  int w = threadIdx.x >> 6, lane = threadIdx.x & 63;
  int lr = lane & 15, lg = lane >> 4;
  int m0 = b*4096 + mb*128 + w*16;
  float scv = scalep[0];
  float sscale = ((scv > 20.f) ? scv : log1pf(__expf(scv))) * 0.0625f; // softplus/sqrt(256)
  v8bf q[8];
#pragma unroll
  for (int kk = 0; kk < 8; kk++)
    q[kk] = *reinterpret_cast<const v8bf*>(qkv + (size_t)(m0 + lr) * 768 + kk*32 + lg*8);
  v4f o[16] = {};
  float den[4] = {0.f, 0.f, 0.f, 0.f};
  const bf16* kpb = kp  + (size_t)b * 2048 * 256;
  const bf16* vpb = vpt + (size_t)b * 256 * 2048;
  for (int kc = 0; kc < 2048; kc += 64) {
    __syncthreads();  // previous iter's LDS reads done
    for (int u = threadIdx.x; u < 2048; u += 512) {   // stage Kp[kc..kc+63][0..255]
      int r = u >> 5, cu = u & 31;
      *reinterpret_cast<v8bf*>(Ks + (size_t)(r*32 + (cu ^ (r & 7))) * 8) =
        *reinterpret_cast<const v8bf*>(kpb + (size_t)(kc + r) * 256 + cu*8);
    }
    for (int u = threadIdx.x; u < 2048; u += 512) {   // stage VpT[0..255][kc..kc+63]
      int r = u >> 3, cu = u & 7;
      *reinterpret_cast<v8bf*>(Vs + (size_t)(r*8 + (cu ^ (r & 7))) * 8) =
        *reinterpret_cast<const v8bf*>(vpb + (size_t)r * 2048 + kc + cu*8);
    }
    __syncthreads();
    // S = Q @ Kp_chunk^T  (D: row=m=lg*4+reg, col=n=lr per 16-tile)
    v4f s4[4] = {};
#pragma unroll
    for (int kk = 0; kk < 8; kk++) {
#pragma unroll
      for (int n = 0; n < 4; n++) {
        int row = n*16 + lr;
        v8bf bk = *reinterpret_cast<const v8bf*>(Ks + (size_t)(row*32 + ((kk*4 + lg) ^ (row & 7))) * 8);
        s4[n] = MFMA(q[kk], bk, s4[n]);
      }
    }
    // P = exp(s*S); accumulate denominator; bounce P through per-wave LDS (swizzled)
#pragma unroll
    for (int n = 0; n < 4; n++) {
#pragma unroll
      for (int r = 0; r < 4; r++) {
        float p = __expf(s4[n][r] * sscale);
        den[r] += p;
        int m = lg*4 + r;
        int ncol = n*16 + lr;
        Ps[w][m*64 + (((ncol >> 3) ^ (m & 7)) << 3) + (ncol & 7)] = (bf16)p;
      }
    }
    v8bf pa[2];  // A-frag of P: m = lr, n = c*32 + lg*8 + j
#pragma unroll
    for (int c = 0; c < 2; c++)
      pa[c] = *reinterpret_cast<const v8bf*>(&Ps[w][lr*64 + (((c*4 + lg) ^ (lr & 7)) << 3)]);
#pragma unroll
    for (int vc = 0; vc < 16; vc++) {
#pragma unroll
      for (int c = 0; c < 2; c++) {
        int row = vc*16 + lr;   // B[n][v]: v = lr -> VpT row, n contiguous
        v8bf bv = *reinterpret_cast<const v8bf*>(Vs + (size_t)(row*8 + ((c*4 + lg) ^ (row & 7))) * 8);
        o[vc] = MFMA(pa[c], bv, o[vc]);
      }
    }
  }
#pragma unroll
  for (int r = 0; r < 4; r++) {
    float d = den[r];
    d += __shfl_xor(d, 1); d += __shfl_xor(d, 2); d += __shfl_xor(d, 4); d += __shfl_xor(d, 8);
    den[r] = d;
  }
#pragma unroll
  for (int vc = 0; vc < 16; vc++)
#pragma unroll
    for (int r = 0; r < 4; r++)
      attn[(size_t)(m0 + lg*4 + r) * 256 + vc*16 + lr] = (bf16)(o[vc][r] / den[r]);
}

// ---------------- K6: out = LN2(tokens + 0.1 * attn @ Wo^T) ----------------
__global__ __launch_bounds__(256) void k_outln(const bf16* __restrict__ attn, const bf16* __restrict__ wob,
                                               const float* __restrict__ tok, const float* __restrict__ g2,
                                               const float* __restrict__ b2, float* __restrict__ out){
  int w = threadIdx.x >> 6, lane = threadIdx.x & 63;
  int lr = lane & 15, lg = lane >> 4;
  int m0 = blockIdx.x * 64 + w * 16;
  v8bf a[8];
#pragma unroll
  for (int kk = 0; kk < 8; kk++)
    a[kk] = *reinterpret_cast<const v8bf*>(attn + (size_t)(m0 + lr) * 256 + kk*32 + lg*8);
  v4f acc[16] = {};
#pragma unroll
  for (int vc = 0; vc < 16; vc++)
#pragma unroll
    for (int kk = 0; kk < 8; kk++) {
      v8bf bv = *reinterpret_cast<const v8bf*>(wob + (size_t)(vc*16 + lr) * 256 + kk*32 + lg*8);
      acc[vc] = MFMA(a[kk], bv, acc[vc]);
    }
  float sum[4] = {0,0,0,0}, ssum[4] = {0,0,0,0};
#pragma unroll
  for (int vc = 0; vc < 16; vc++)
#pragma unroll
    for (int r = 0; r < 4; r++) {
      float t = tok[(size_t)(m0 + lg*4 + r) * 256 + vc*16 + lr];
      float x = t + 0.1f * acc[vc][r];
      acc[vc][r] = x;
      sum[r] += x; ssum[r] += x*x;
    }
#pragma unroll
  for (int r = 0; r < 4; r++) {
    float s_ = sum[r], q_ = ssum[r];
    s_ += __shfl_xor(s_, 1); s_ += __shfl_xor(s_, 2); s_ += __shfl_xor(s_, 4); s_ += __shfl_xor(s_, 8);
    q_ += __shfl_xor(q_, 1); q_ += __shfl_xor(q_, 2); q_ += __shfl_xor(q_, 4); q_ += __shfl_xor(q_, 8);
    sum[r] = s_ * (1.0f/256.0f); ssum[r] = q_ * (1.0f/256.0f);
  }
#pragma unroll
  for (int vc = 0; vc < 16; vc++) {
    float g = g2[vc*16 + lr], bb = b2[vc*16 + lr];
#pragma unroll
    for (int r = 0; r < 4; r++) {
      float mean = sum[r];
      float var  = ssum[r] - mean*mean;
      float inv  = rsqrtf(var + 1e-5f);
      out[(size_t)(m0 + lg*4 + r) * 256 + vc*16 + lr] = (acc[vc][r] - mean) * inv * g + bb;
    }
  }
}

// ---------------- launch ----------------
extern "C" void kernel_launch(void* const* d_in, const int* in_sizes, int n_in,
                              void* d_out, int out_size, void* d_ws, size_t ws_size,
                              hipStream_t stream){
  (void)in_sizes; (void)n_in; (void)out_size; (void)ws_size;
  const float* tok = (const float*)d_in[0];
  const float* wq  = (const float*)d_in[1];
  const float* wk  = (const float*)d_in[2];
  const float* wv  = (const float*)d_in[3];
  const float* wo  = (const float*)d_in[4];
  const float* E   = (const float*)d_in[5];
  const float* F   = (const float*)d_in[6];
  const float* g1  = (const float*)d_in[7];
  const float* b1  = (const float*)d_in[8];
  const float* g2  = (const float*)d_in[9];
  const float* b2  = (const float*)d_in[10];
  const float* sc  = (const float*)d_in[11];
  float* out = (float*)d_out;
  char* ws = (char*)d_ws;
  // ws layout (bytes), total 84,443,136
  bf16* tn   = (bf16*)(ws + 0);          // [32768][256] tn; reused as attn output
  bf16* qkv  = (bf16*)(ws + 16777216);   // [32768][768]
  bf16* kp   = (bf16*)(ws + 67108864);   // [16384][256]
  bf16* vpt  = (bf16*)(ws + 75497472);   // [2048][2048]
  bf16* wqkv = (bf16*)(ws + 83886080);   // [768][256]
  bf16* wob  = (bf16*)(ws + 84279296);   // [256][256]
  bf16* ebf  = (bf16*)(ws + 84410368);   // [64][128]
  bf16* fbf  = (bf16*)(ws + 84426752);   // [64][128]
  bf16* attn = tn;                       // alias: tn dead after k_qkv

  k_prep <<<768,  256, 0, stream>>>(wq, wk, wv, wo, E, F, wqkv, wob, ebf, fbf);
  k_ln1  <<<8192, 256, 0, stream>>>(tok, g1, b1, tn);
  k_qkv  <<<dim3(256, 6), 256, 0, stream>>>(tn, wqkv, qkv);
  k_l2n  <<<16384, 256, 0, stream>>>(qkv);
  k_kproj<<<256,  256, 0, stream>>>(qkv, ebf, kp);
  k_vproj<<<256,  256, 0, stream>>>(qkv, fbf, vpt);
  k_attn <<<256,  512, 0, stream>>>(qkv, kp, vpt, sc, attn);
  k_outln<<<512,  256, 0, stream>>>(attn, wob, tok, g2, b2, out);
}

// Round 2
// 292.543 us; speedup vs baseline: 1.0052x; 1.0052x over previous
//
#include <hip/hip_runtime.h>
#include <hip/hip_bf16.h>

// LowRankSoftmaxAttentionBlock round 2:
//  - k_attn: 2-way KV split (grid 512 -> 2 blocks/CU), unnormalized bf16 partials +
//    f32 den partials, normalization folded into k_outln. XCD batch affinity.
//  - k_qkv: fused row-l2norm epilogue (Q,K); K,V stored transposed [b][h][n].
//  - kproj/vproj: all-contiguous 16B fragment loads; vproj 8B vector stores.
// MFMA: v_mfma_f32_16x16x32_bf16. A/B frag: own-idx = lane&15, k = (lane>>4)*8+j.
// C/D: col = lane&15, row = (lane>>4)*4 + reg.

typedef __bf16 bf16;
typedef __bf16 v8bf __attribute__((ext_vector_type(8)));
typedef __bf16 v4bf __attribute__((ext_vector_type(4)));
typedef float  v4f  __attribute__((ext_vector_type(4)));

#define MFMA(a,b,c) __builtin_amdgcn_mfma_f32_16x16x32_bf16((a),(b),(c),0,0,0)

// ---------------- K0: convert weights to bf16 ----------------
__global__ __launch_bounds__(256) void k_prep(const float* __restrict__ wq, const float* __restrict__ wk,
                       const float* __restrict__ wv, const float* __restrict__ wo,
                       const float* __restrict__ E,  const float* __restrict__ F,
                       bf16* __restrict__ wqkv, bf16* __restrict__ wob,
                       bf16* __restrict__ ebf,  bf16* __restrict__ fbf){
  int i = blockIdx.x * 256 + threadIdx.x;          // 0..196607
  float v;
  if (i < 65536)       v = wq[i];
  else if (i < 131072) v = wk[i - 65536];
  else                 v = wv[i - 131072];
  wqkv[i] = (bf16)v;
  if (i < 65536) wob[i] = (bf16)wo[i];
  if (i < 8192) { ebf[i] = (bf16)E[i]; fbf[i] = (bf16)F[i]; }
}

// ---------------- K1: LayerNorm1 -> tn (bf16) ----------------
__global__ __launch_bounds__(256) void k_ln1(const float* __restrict__ tok, const float* __restrict__ g1,
                      const float* __restrict__ b1, bf16* __restrict__ tn){
  int row  = blockIdx.x * 4 + (threadIdx.x >> 6);
  int lane = threadIdx.x & 63;
  float4 x = *reinterpret_cast<const float4*>(tok + (size_t)row * 256 + lane * 4);
  float s  = x.x + x.y + x.z + x.w;
  float ss = x.x*x.x + x.y*x.y + x.z*x.z + x.w*x.w;
  for (int o = 1; o < 64; o <<= 1) { s += __shfl_xor(s, o); ss += __shfl_xor(ss, o); }
  float mean = s * (1.0f/256.0f);
  float var  = ss * (1.0f/256.0f) - mean*mean;
  float inv  = rsqrtf(var + 1e-5f);
  float4 g  = *reinterpret_cast<const float4*>(g1 + lane*4);
  float4 bb = *reinterpret_cast<const float4*>(b1 + lane*4);
  v4bf o4;
  o4[0] = (bf16)((x.x-mean)*inv*g.x + bb.x);
  o4[1] = (bf16)((x.y-mean)*inv*g.y + bb.y);
  o4[2] = (bf16)((x.z-mean)*inv*g.z + bb.z);
  o4[3] = (bf16)((x.w-mean)*inv*g.w + bb.w);
  *reinterpret_cast<v4bf*>(tn + (size_t)row * 256 + lane * 4) = o4;
}

// ---------------- K2: QKV GEMM + fused l2norm; Q row-major, K/V transposed ----------------
// grid (256, 3): bm x seg(0=Q,1=K,2=V). block 512 = 8 waves (2 wr x 4 wc), 128 rows x 256 cols.
__global__ __launch_bounds__(512) void k_qkv(const bf16* __restrict__ tn, const bf16* __restrict__ w,
                                             bf16* __restrict__ Qn, bf16* __restrict__ kT,
                                             bf16* __restrict__ vT){
  __shared__ float ssL[2][4][64];
  int bm = blockIdx.x, seg = blockIdx.y;
  int wid = threadIdx.x >> 6, lane = threadIdx.x & 63;
  int wr = wid >> 2, wc = wid & 3;
  int row0 = bm * 128 + wr * 64;
  int col0 = wc * 64;
  int lr = lane & 15, lg = lane >> 4;
  const bf16* wseg = w + (size_t)seg * 65536;
  v4f acc[4][4] = {};
  for (int k0 = 0; k0 < 256; k0 += 32) {
    v8bf a[4], b[4];
#pragma unroll
    for (int mi = 0; mi < 4; mi++)
      a[mi] = *reinterpret_cast<const v8bf*>(tn + (size_t)(row0 + mi*16 + lr) * 256 + k0 + lg*8);
#pragma unroll
    for (int ni = 0; ni < 4; ni++)
      b[ni] = *reinterpret_cast<const v8bf*>(wseg + (size_t)(col0 + ni*16 + lr) * 256 + k0 + lg*8);
#pragma unroll
    for (int mi = 0; mi < 4; mi++)
#pragma unroll
      for (int ni = 0; ni < 4; ni++)
        acc[mi][ni] = MFMA(a[mi], b[ni], acc[mi][ni]);
  }
  if (seg < 2) {   // row l2norm across the 4 wc waves
#pragma unroll
    for (int mi = 0; mi < 4; mi++)
#pragma unroll
      for (int q = 0; q < 4; q++) {
        float s = acc[mi][0][q]*acc[mi][0][q] + acc[mi][1][q]*acc[mi][1][q]
                + acc[mi][2][q]*acc[mi][2][q] + acc[mi][3][q]*acc[mi][3][q];
        s += __shfl_xor(s, 1); s += __shfl_xor(s, 2); s += __shfl_xor(s, 4); s += __shfl_xor(s, 8);
        if (lr == 0) ssL[wr][wc][mi*16 + lg*4 + q] = s;
      }
    __syncthreads();
#pragma unroll
    for (int mi = 0; mi < 4; mi++)
#pragma unroll
      for (int q = 0; q < 4; q++) {
        int idx = mi*16 + lg*4 + q;
        float tot = ssL[wr][0][idx] + ssL[wr][1][idx] + ssL[wr][2][idx] + ssL[wr][3][idx];
        float inv = rsqrtf(fmaxf(tot, 1e-24f));
#pragma unroll
        for (int ni = 0; ni < 4; ni++) acc[mi][ni][q] *= inv;
      }
  }
  if (seg == 0) {
#pragma unroll
    for (int mi = 0; mi < 4; mi++)
#pragma unroll
      for (int ni = 0; ni < 4; ni++)
#pragma unroll
        for (int q = 0; q < 4; q++)
          Qn[(size_t)(row0 + mi*16 + lg*4 + q) * 256 + col0 + ni*16 + lr] = (bf16)acc[mi][ni][q];
  } else {
    bf16* dst = (seg == 1) ? kT : vT;
    int batch = row0 >> 12;
    int nloc  = row0 & 4095;
#pragma unroll
    for (int mi = 0; mi < 4; mi++)
#pragma unroll
      for (int ni = 0; ni < 4; ni++) {
        v4bf o4;
        o4[0]=(bf16)acc[mi][ni][0]; o4[1]=(bf16)acc[mi][ni][1];
        o4[2]=(bf16)acc[mi][ni][2]; o4[3]=(bf16)acc[mi][ni][3];
        *reinterpret_cast<v4bf*>(dst + ((size_t)batch*256 + col0 + ni*16 + lr) * 4096
                                     + nloc + mi*16 + lg*4) = o4;
      }
  }
}

// ---------------- K4a: kp[b][k=2048][h=256] = E @ K_blk, from kT[b][h][n] ----------------
__global__ __launch_bounds__(256) void k_kproj(const bf16* __restrict__ kT, const bf16* __restrict__ ebf,
                                               bf16* __restrict__ kp){
  int b = blockIdx.x >> 5, blk = blockIdx.x & 31;
  int w = threadIdx.x >> 6, lane = threadIdx.x & 63;
  int lr = lane & 15, lg = lane >> 4;
  const bf16* kb = kT + (size_t)b * 256 * 4096 + blk * 128;
  v8bf a[4][4];
#pragma unroll
  for (int kt = 0; kt < 4; kt++)
#pragma unroll
    for (int sc = 0; sc < 4; sc++)
      a[kt][sc] = *reinterpret_cast<const v8bf*>(ebf + (size_t)(kt*16 + lr) * 128 + sc*32 + lg*8);
  v4f acc[4][4] = {};
#pragma unroll
  for (int nt = 0; nt < 4; nt++) {
    int ht = w*4 + nt;
#pragma unroll
    for (int sc = 0; sc < 4; sc++) {
      v8bf bfrag = *reinterpret_cast<const v8bf*>(kb + (size_t)(ht*16 + lr) * 4096 + sc*32 + lg*8);
#pragma unroll
      for (int kt = 0; kt < 4; kt++)
        acc[kt][nt] = MFMA(a[kt][sc], bfrag, acc[kt][nt]);
    }
  }
#pragma unroll
  for (int kt = 0; kt < 4; kt++)
#pragma unroll
    for (int nt = 0; nt < 4; nt++)
#pragma unroll
      for (int q = 0; q < 4; q++)
        kp[(size_t)(b*2048 + blk*64 + kt*16 + lg*4 + q) * 256 + w*64 + nt*16 + lr] = (bf16)acc[kt][nt][q];
}

// ---------------- K4b: vpt[b][h=256][k=2048] = (F @ V_blk)^T, from vT[b][h][n] ----------------
__global__ __launch_bounds__(256) void k_vproj(const bf16* __restrict__ vT, const bf16* __restrict__ fbf,
                                               bf16* __restrict__ vpt){
  int b = blockIdx.x >> 5, blk = blockIdx.x & 31;
  int w = threadIdx.x >> 6, lane = threadIdx.x & 63;
  int lr = lane & 15, lg = lane >> 4;
  const bf16* vb = vT + (size_t)b * 256 * 4096 + blk * 128;
  v8bf a[4][4];
#pragma unroll
  for (int kt = 0; kt < 4; kt++)
#pragma unroll
    for (int sc = 0; sc < 4; sc++)
      a[kt][sc] = *reinterpret_cast<const v8bf*>(fbf + (size_t)(kt*16 + lr) * 128 + sc*32 + lg*8);
  v4f acc[4][4] = {};   // [nt][kt]
#pragma unroll
  for (int nt = 0; nt < 4; nt++) {
    int ht = w*4 + nt;
#pragma unroll
    for (int sc = 0; sc < 4; sc++) {
      v8bf bfrag = *reinterpret_cast<const v8bf*>(vb + (size_t)(ht*16 + lr) * 4096 + sc*32 + lg*8);
#pragma unroll
      for (int kt = 0; kt < 4; kt++)
        acc[nt][kt] = MFMA(a[kt][sc], bfrag, acc[nt][kt]);
    }
  }
#pragma unroll
  for (int nt = 0; nt < 4; nt++)
#pragma unroll
    for (int kt = 0; kt < 4; kt++) {
      v4bf o4;
      o4[0]=(bf16)acc[nt][kt][0]; o4[1]=(bf16)acc[nt][kt][1];
      o4[2]=(bf16)acc[nt][kt][2]; o4[3]=(bf16)acc[nt][kt][3];
      *reinterpret_cast<v4bf*>(vpt + ((size_t)b*256 + w*64 + nt*16 + lr) * 2048
                                   + blk*64 + kt*16 + lg*4) = o4;
    }
}

// ---------------- K5: attention, 2-way KV split. grid 512: batch=bid&7 (XCD affinity) ----------------
__global__ __launch_bounds__(512) void k_attn(const bf16* __restrict__ Qn, const bf16* __restrict__ kp,
                                              const bf16* __restrict__ vpt, const float* __restrict__ scalep,
                                              bf16* __restrict__ attnP, float* __restrict__ denP){
  __shared__ __align__(16) bf16 Ks[64 * 256];   // Kp chunk, XOR-swizzled 16B units
  __shared__ __align__(16) bf16 Vs[256 * 64];   // VpT chunk, XOR-swizzled 16B units
  __shared__ __align__(16) bf16 Ps[8][16 * 64]; // per-wave P (swizzled)
  int bid = blockIdx.x;
  int b = bid & 7, half = (bid >> 3) & 1, mb = bid >> 4;
  int w = threadIdx.x >> 6, lane = threadIdx.x & 63;
  int lr = lane & 15, lg = lane >> 4;
  int m0 = b*4096 + mb*128 + w*16;
  int kc0 = half * 1024;
  float scv = scalep[0];
  float sscale = ((scv > 20.f) ? scv : log1pf(__expf(scv))) * 0.0625f; // softplus/sqrt(256)
  v8bf q[8];
#pragma unroll
  for (int kk = 0; kk < 8; kk++)
    q[kk] = *reinterpret_cast<const v8bf*>(Qn + (size_t)(m0 + lr) * 256 + kk*32 + lg*8);
  v4f o[16] = {};
  float den[4] = {0.f, 0.f, 0.f, 0.f};
  const bf16* kpb = kp  + (size_t)b * 2048 * 256;
  const bf16* vpb = vpt + (size_t)b * 256 * 2048;
  for (int kc = kc0; kc < kc0 + 1024; kc += 64) {
    __syncthreads();  // previous iter's LDS reads done
    for (int u = threadIdx.x; u < 2048; u += 512) {   // stage Kp[kc..kc+63][0..255]
      int r = u >> 5, cu = u & 31;
      *reinterpret_cast<v8bf*>(Ks + (size_t)(r*32 + (cu ^ (r & 7))) * 8) =
        *reinterpret_cast<const v8bf*>(kpb + (size_t)(kc + r) * 256 + cu*8);
    }
    for (int u = threadIdx.x; u < 2048; u += 512) {   // stage VpT[0..255][kc..kc+63]
      int r = u >> 3, cu = u & 7;
      *reinterpret_cast<v8bf*>(Vs + (size_t)(r*8 + (cu ^ (r & 7))) * 8) =
        *reinterpret_cast<const v8bf*>(vpb + (size_t)r * 2048 + kc + cu*8);
    }
    __syncthreads();
    // S = Q @ Kp_chunk^T
    v4f s4[4] = {};
    __builtin_amdgcn_s_setprio(1);
#pragma unroll
    for (int kk = 0; kk < 8; kk++) {
#pragma unroll
      for (int n = 0; n < 4; n++) {
        int row = n*16 + lr;
        v8bf bk = *reinterpret_cast<const v8bf*>(Ks + (size_t)(row*32 + ((kk*4 + lg) ^ (row & 7))) * 8);
        s4[n] = MFMA(q[kk], bk, s4[n]);
      }
    }
    __builtin_amdgcn_s_setprio(0);
    // P = exp(s*S); accumulate denominator; bounce P through per-wave LDS
#pragma unroll
    for (int n = 0; n < 4; n++) {
#pragma unroll
      for (int r = 0; r < 4; r++) {
        float p = __expf(s4[n][r] * sscale);
        den[r] += p;
        int m = lg*4 + r;
        int ncol = n*16 + lr;
        Ps[w][m*64 + (((ncol >> 3) ^ (m & 7)) << 3) + (ncol & 7)] = (bf16)p;
      }
    }
    v8bf pa[2];  // A-frag of P: m = lr, k = c*32 + lg*8 + j
#pragma unroll
    for (int c = 0; c < 2; c++)
      pa[c] = *reinterpret_cast<const v8bf*>(&Ps[w][lr*64 + (((c*4 + lg) ^ (lr & 7)) << 3)]);
    __builtin_amdgcn_s_setprio(1);
#pragma unroll
    for (int vc = 0; vc < 16; vc++) {
#pragma unroll
      for (int c = 0; c < 2; c++) {
        int row = vc*16 + lr;
        v8bf bv = *reinterpret_cast<const v8bf*>(Vs + (size_t)(row*8 + ((c*4 + lg) ^ (row & 7))) * 8);
        o[vc] = MFMA(pa[c], bv, o[vc]);
      }
    }
    __builtin_amdgcn_s_setprio(0);
  }
#pragma unroll
  for (int r = 0; r < 4; r++) {
    float d = den[r];
    d += __shfl_xor(d, 1); d += __shfl_xor(d, 2); d += __shfl_xor(d, 4); d += __shfl_xor(d, 8);
    den[r] = d;
  }
  size_t obase = (size_t)half * 32768 * 256;
#pragma unroll
  for (int vc = 0; vc < 16; vc++)
#pragma unroll
    for (int r = 0; r < 4; r++)
      attnP[obase + (size_t)(m0 + lg*4 + r) * 256 + vc*16 + lr] = (bf16)o[vc][r];
  if (lr == 0) {
#pragma unroll
    for (int r = 0; r < 4; r++)
      denP[half*32768 + m0 + lg*4 + r] = den[r];
  }
}

// ---------------- K6: out = LN2(tokens + 0.1 * ((o0+o1)/(d0+d1)) @ Wo^T) ----------------
__global__ __launch_bounds__(256) void k_outln(const bf16* __restrict__ attnP, const float* __restrict__ denP,
                                               const bf16* __restrict__ wob, const float* __restrict__ tok,
                                               const float* __restrict__ g2, const float* __restrict__ b2,
                                               float* __restrict__ out){
  int w = threadIdx.x >> 6, lane = threadIdx.x & 63;
  int lr = lane & 15, lg = lane >> 4;
  int m0 = blockIdx.x * 64 + w * 16;
  v8bf a[8];
#pragma unroll
  for (int kk = 0; kk < 8; kk++) {
    v8bf x0 = *reinterpret_cast<const v8bf*>(attnP + (size_t)(m0 + lr) * 256 + kk*32 + lg*8);
    v8bf x1 = *reinterpret_cast<const v8bf*>(attnP + (size_t)32768*256 + (size_t)(m0 + lr) * 256 + kk*32 + lg*8);
#pragma unroll
    for (int j = 0; j < 8; j++) a[kk][j] = (bf16)((float)x0[j] + (float)x1[j]);
  }
  float dden[4];
#pragma unroll
  for (int r = 0; r < 4; r++) {
    int row = m0 + lg*4 + r;
    dden[r] = denP[row] + denP[32768 + row];
  }
  v4f acc[16] = {};
#pragma unroll
  for (int vc = 0; vc < 16; vc++)
#pragma unroll
    for (int kk = 0; kk < 8; kk++) {
      v8bf bv = *reinterpret_cast<const v8bf*>(wob + (size_t)(vc*16 + lr) * 256 + kk*32 + lg*8);
      acc[vc] = MFMA(a[kk], bv, acc[vc]);
    }
  float sum[4] = {0,0,0,0}, ssum[4] = {0,0,0,0};
#pragma unroll
  for (int vc = 0; vc < 16; vc++)
#pragma unroll
    for (int r = 0; r < 4; r++) {
      float t = tok[(size_t)(m0 + lg*4 + r) * 256 + vc*16 + lr];
      float x = t + 0.1f * (acc[vc][r] / dden[r]);
      acc[vc][r] = x;
      sum[r] += x; ssum[r] += x*x;
    }
#pragma unroll
  for (int r = 0; r < 4; r++) {
    float s_ = sum[r], q_ = ssum[r];
    s_ += __shfl_xor(s_, 1); s_ += __shfl_xor(s_, 2); s_ += __shfl_xor(s_, 4); s_ += __shfl_xor(s_, 8);
    q_ += __shfl_xor(q_, 1); q_ += __shfl_xor(q_, 2); q_ += __shfl_xor(q_, 4); q_ += __shfl_xor(q_, 8);
    sum[r] = s_ * (1.0f/256.0f); ssum[r] = q_ * (1.0f/256.0f);
  }
#pragma unroll
  for (int vc = 0; vc < 16; vc++) {
    float g = g2[vc*16 + lr], bb = b2[vc*16 + lr];
#pragma unroll
    for (int r = 0; r < 4; r++) {
      float mean = sum[r];
      float var  = ssum[r] - mean*mean;
      float inv  = rsqrtf(var + 1e-5f);
      out[(size_t)(m0 + lg*4 + r) * 256 + vc*16 + lr] = (acc[vc][r] - mean) * inv * g + bb;
    }
  }
}

// ---------------- launch ----------------
extern "C" void kernel_launch(void* const* d_in, const int* in_sizes, int n_in,
                              void* d_out, int out_size, void* d_ws, size_t ws_size,
                              hipStream_t stream){
  (void)in_sizes; (void)n_in; (void)out_size; (void)ws_size;
  const float* tok = (const float*)d_in[0];
  const float* wq  = (const float*)d_in[1];
  const float* wk  = (const float*)d_in[2];
  const float* wv  = (const float*)d_in[3];
  const float* wo  = (const float*)d_in[4];
  const float* E   = (const float*)d_in[5];
  const float* F   = (const float*)d_in[6];
  const float* g1  = (const float*)d_in[7];
  const float* b1  = (const float*)d_in[8];
  const float* g2  = (const float*)d_in[9];
  const float* b2  = (const float*)d_in[10];
  const float* sc  = (const float*)d_in[11];
  float* out = (float*)d_out;
  char* ws = (char*)d_ws;
  // ws layout (bytes), total 84,443,136 (same footprint as round 1)
  bf16* tn   = (bf16*)(ws + 0);          // [32768][256] ; reused as attnP half 0
  bf16* Qn   = (bf16*)(ws + 16777216);   // [32768][256] normalized Q
  bf16* kT   = (bf16*)(ws + 33554432);   // [8][256][4096] ; reused as attnP half 1
  bf16* vT   = (bf16*)(ws + 50331648);   // [8][256][4096] ; head reused as denP
  bf16* kp   = (bf16*)(ws + 67108864);   // [8][2048][256]
  bf16* vpt  = (bf16*)(ws + 75497472);   // [8][256][2048]
  bf16* wqkv = (bf16*)(ws + 83886080);   // [768][256]
  bf16* wob  = (bf16*)(ws + 84279296);   // [256][256]
  bf16* ebf  = (bf16*)(ws + 84410368);   // [64][128]
  bf16* fbf  = (bf16*)(ws + 84426752);   // [64][128]
  bf16*  attnP = tn;                     // [2][32768][256] spans tn+Qn? NO: half1 -> kT
  float* denP  = (float*)vT;             // [2][32768] f32 (vT dead after k_vproj)

  k_prep <<<768,  256, 0, stream>>>(wq, wk, wv, wo, E, F, wqkv, wob, ebf, fbf);
  k_ln1  <<<8192, 256, 0, stream>>>(tok, g1, b1, tn);
  k_qkv  <<<dim3(256, 3), 512, 0, stream>>>(tn, wqkv, Qn, kT, vT);
  k_kproj<<<256,  256, 0, stream>>>(kT, ebf, kp);
  k_vproj<<<256,  256, 0, stream>>>(vT, fbf, vpt);
  // attnP half0 -> tn region (dead), half1 -> kT region (dead). They are NOT
  // contiguous, but k_attn/k_outln index half via explicit base: half0 base = tn,
  // half1 base = tn + 32768*256 elements == Qn region... (Qn is live!) -> use kT:
  // pass tn as base; half1 offset 32768*256 elems lands exactly at Qn. To avoid
  // clobbering Qn, instead launch with base tn only if halves contiguous.
  // Safe mapping: halves must be contiguous -> place attnP at kT (16MB) + vT(16MB):
  // both dead after projections, contiguous 32MB. denP -> tail of vpt? vpt live.
  // Final: attnP = kT region (spans kT+vT = 32MB contiguous), denP = tn region (dead after k_qkv).
  {
    bf16*  attnP2 = kT;                  // [2][32768][256] over kT..vT (32MB, both dead)
    float* denP2  = (float*)tn;          // [2][32768] f32 (tn dead after k_qkv)
    k_attn <<<512,  512, 0, stream>>>(Qn, kp, vpt, sc, attnP2, denP2);
    k_outln<<<512,  256, 0, stream>>>(attnP2, denP2, wob, tok, g2, b2, out);
  }
  (void)attnP; (void)denP;
}